// Round 2
// baseline (254.563 us; speedup 1.0000x reference)
//
#include <hip/hip_runtime.h>

// ---------------------------------------------------------------------------
// FlexBertUnpadRopeAttention  (B=8, S=1024, H=16, D=64, HIDDEN=1024, win=±64)
//   1) cvt fp32->bf16 (hidden, Wqkv, Wo)
//   2) gemm_qkv_rope: qkv = hidden @ Wqkv^T, fused RoPE(+q*0.125), writes
//      q[b,h,s,d], k[b,h,s,d], v^T[b,h,d,s]  (bf16)
//   3) attn_win: 64-query tile vs 192-key window, exact softmax, MFMA
//   4) gemm_out: out = attn @ Wo^T  (fp32 out)
// MFMA 16x16x32 bf16 layouts (HW-verified):
//   A: lane holds A[m=lane&15][k=quad*8+j]   (16B row-contiguous)
//   B: lane holds B[k=quad*8+j][n=lane&15]   (16B row-contiguous in K)
//   C/D: lane holds D[row=quad*4+reg][col=lane&15]
// R1 fix: K-tile staging covered only k=0..31 (4 chunks/row); rows are 64
// shorts = 8 chunks. Second score-MFMA read uninit LDS -> NaN. Now 6x256.
// ---------------------------------------------------------------------------

typedef __attribute__((ext_vector_type(8))) short short8;
typedef __attribute__((ext_vector_type(4))) float f32x4;

#define SEQ   1024
#define NHEAD 16
#define HEADD 64
#define NTOK  8192

__device__ __forceinline__ unsigned short f2bf(float x) {
  unsigned u = __float_as_uint(x);
  u += 0x7fffu + ((u >> 16) & 1u);          // RNE
  return (unsigned short)(u >> 16);
}

__device__ __forceinline__ void gload_lds16(const void* g, void* l) {
  __builtin_amdgcn_global_load_lds((__attribute__((address_space(1))) void*)(g),
                                   (__attribute__((address_space(3))) void*)(l),
                                   16, 0, 0);
}

// ---------------------------------------------------------------- cvt ------
__global__ __launch_bounds__(256) void cvt_bf16(const float* __restrict__ in,
                                                unsigned short* __restrict__ out,
                                                int n4) {
  int i = blockIdx.x * 256 + threadIdx.x;
  if (i < n4) {
    float4 v = ((const float4*)in)[i];
    ushort4 o;
    o.x = f2bf(v.x); o.y = f2bf(v.y); o.z = f2bf(v.z); o.w = f2bf(v.w);
    ((ushort4*)out)[i] = o;
  }
}

// --------------------------------------------------------- gemm1 + rope ----
__global__ __launch_bounds__(256) void gemm_qkv_rope(
    const unsigned short* __restrict__ A,   // [8192][1024] bf16
    const unsigned short* __restrict__ W,   // [3072][1024] bf16
    unsigned short* __restrict__ qb,        // [B][H][S][D]
    unsigned short* __restrict__ kb,        // [B][H][S][D]
    unsigned short* __restrict__ vt)        // [B][H][D][S]
{
  __shared__ unsigned short As[128 * 32];
  __shared__ unsigned short Bs[128 * 32];
  const int tid  = threadIdx.x;
  const int wave = tid >> 6, lane = tid & 63;
  const int quad = lane >> 4, l15 = lane & 15;
  const int row0 = blockIdx.y * 128;
  const int col0 = blockIdx.x * 128;
  const int mrow = (wave >> 1) * 64;        // wave M offset in tile
  const int ncol = (wave & 1) * 64;         // wave N offset in tile

  f32x4 acc[4][4];
#pragma unroll
  for (int i = 0; i < 4; i++)
#pragma unroll
    for (int j = 0; j < 4; j++) acc[i][j] = (f32x4){0.f, 0.f, 0.f, 0.f};

  for (int k0 = 0; k0 < 1024; k0 += 32) {
#pragma unroll
    for (int i = 0; i < 2; i++) {           // stage 8KB A + 8KB B, 16B/lane
      int p = i * 256 + tid;
      int r = p >> 2, c = p & 3;
      gload_lds16(A + (size_t)(row0 + r) * 1024 + k0 + c * 8, &As[p * 8]);
      gload_lds16(W + (size_t)(col0 + r) * 1024 + k0 + c * 8, &Bs[p * 8]);
    }
    __syncthreads();
    short8 af[4], bf[4];
#pragma unroll
    for (int mt = 0; mt < 4; mt++)
      af[mt] = *(const short8*)&As[(mrow + mt * 16 + l15) * 32 + quad * 8];
#pragma unroll
    for (int nt = 0; nt < 4; nt++)
      bf[nt] = *(const short8*)&Bs[(ncol + nt * 16 + l15) * 32 + quad * 8];
#pragma unroll
    for (int mt = 0; mt < 4; mt++)
#pragma unroll
      for (int nt = 0; nt < 4; nt++)
        acc[mt][nt] = __builtin_amdgcn_mfma_f32_16x16x32_bf16(af[mt], bf[nt],
                                                              acc[mt][nt], 0, 0, 0);
    __syncthreads();
  }

  // epilogue: this wave's 64 cols == one head of one {q,k,v} section
  const int colw  = col0 + ncol;            // multiple of 64
  const int which = colw >> 10;             // 0=q 1=k 2=v
  const int h     = (colw >> 6) & 15;
  const int rowg  = row0 + mrow;

  if (which == 2) {                         // V: transposed, 8B-packed stores
#pragma unroll
    for (int mt = 0; mt < 4; mt++) {
      int rbase = rowg + mt * 16 + quad * 4;
      int b = rbase >> 10, s = rbase & 1023;
#pragma unroll
      for (int c = 0; c < 4; c++) {
        int d = c * 16 + l15;
        ushort4 o;
        o.x = f2bf(acc[mt][c][0]); o.y = f2bf(acc[mt][c][1]);
        o.z = f2bf(acc[mt][c][2]); o.w = f2bf(acc[mt][c][3]);
        *(ushort4*)&vt[((size_t)((b * 16 + h) * 64 + d)) * 1024 + s] = o;
      }
    }
  } else {                                  // Q/K: in-register RoPE
    unsigned short* dst = (which == 0) ? qb : kb;
    const float scale = (which == 0) ? 0.125f : 1.0f;
    // inv_freq = 10000^(-d/32) = 2^(-d*log2(10000)/32)
    const float kf = 0.41524101186092034f;
    float inv0 = exp2f(-(float)l15 * kf);
    float inv1 = exp2f(-(float)(l15 + 16) * kf);
#pragma unroll
    for (int mt = 0; mt < 4; mt++) {
#pragma unroll
      for (int r = 0; r < 4; r++) {
        int row = rowg + mt * 16 + quad * 4 + r;
        int b = row >> 10, s = row & 1023;
        size_t base = (size_t)((b * 16 + h) * 1024 + s) * 64;
        float sn0, cs0, sn1, cs1;
        sincosf((float)s * inv0, &sn0, &cs0);
        sincosf((float)s * inv1, &sn1, &cs1);
        float x1a = acc[mt][0][r], x2a = acc[mt][2][r];   // d=l15, d+32
        float x1b = acc[mt][1][r], x2b = acc[mt][3][r];   // d=16+l15, d+32
        dst[base + l15]           = f2bf((x1a * cs0 - x2a * sn0) * scale);
        dst[base + 32 + l15]      = f2bf((x2a * cs0 + x1a * sn0) * scale);
        dst[base + 16 + l15]      = f2bf((x1b * cs1 - x2b * sn1) * scale);
        dst[base + 48 + l15]      = f2bf((x2b * cs1 + x1b * sn1) * scale);
      }
    }
  }
}

// ------------------------------------------------------------- attention ---
__global__ __launch_bounds__(256) void attn_win(
    const unsigned short* __restrict__ qb,
    const unsigned short* __restrict__ kb,
    const unsigned short* __restrict__ vt,
    const int* __restrict__ am,             // attn_mask [B][S]
    unsigned short* __restrict__ ob)        // [8192][1024] bf16
{
  __shared__ unsigned short Ks[192 * 72];    // keys, +8 pad
  __shared__ unsigned short Vs[64 * 200];    // V^T,  +8 pad
  __shared__ unsigned short Ps[4][16 * 200]; // per-wave P, +8 pad
  __shared__ unsigned short smask[192];

  const int tid  = threadIdx.x;
  const int wave = tid >> 6, lane = tid & 63;
  const int quad = lane >> 4, l15 = lane & 15;
  const int qs = blockIdx.x * 64;
  const int h  = blockIdx.y, b = blockIdx.z;
  const size_t hb = (size_t)(b * 16 + h);
  const unsigned short* Qg = qb + hb * SEQ * 64;
  const unsigned short* Kg = kb + hb * SEQ * 64;
  const unsigned short* Vg = vt + hb * 64 * SEQ;
  const int t0 = qs - 64;

  // stage K: 192 rows x 8 chunks(16B) = full 64-dim rows  (R1 fix)
#pragma unroll
  for (int i = 0; i < 6; i++) {
    int p = i * 256 + tid;
    int r = p >> 3, c = p & 7;
    int t = t0 + r; t = t < 0 ? 0 : (t > 1023 ? 1023 : t);   // garbage masked
    *(short8*)&Ks[r * 72 + c * 8] = *(const short8*)&Kg[(size_t)t * 64 + c * 8];
  }
  // stage V^T: 64 rows x 24 chunks
#pragma unroll
  for (int i = 0; i < 6; i++) {
    int p = i * 256 + tid;
    int d = p / 24, c = p % 24;
    int t = t0 + c * 8; t = t < 0 ? 0 : (t > 1016 ? 1016 : t);
    *(short8*)&Vs[d * 200 + c * 8] = *(const short8*)&Vg[(size_t)d * SEQ + t];
  }
  if (tid < 192) {
    int t = t0 + tid;
    smask[tid] = (t >= 0 && t < SEQ) ? (unsigned short)(am[b * SEQ + t] != 0) : 0;
  }
  __syncthreads();

  // Q fragments straight from global (A-operand is row-contiguous)
  const int qw = qs + wave * 16;
  short8 qf0 = *(const short8*)&Qg[(size_t)(qw + l15) * 64 + quad * 8];
  short8 qf1 = *(const short8*)&Qg[(size_t)(qw + l15) * 64 + 32 + quad * 8];

  // scores: 16 x 192
  f32x4 sc[12];
#pragma unroll
  for (int tt = 0; tt < 12; tt++) {
    short8 b0 = *(const short8*)&Ks[(tt * 16 + l15) * 72 + quad * 8];
    short8 b1 = *(const short8*)&Ks[(tt * 16 + l15) * 72 + 32 + quad * 8];
    f32x4 a = (f32x4){0.f, 0.f, 0.f, 0.f};
    a = __builtin_amdgcn_mfma_f32_16x16x32_bf16(qf0, b0, a, 0, 0, 0);
    a = __builtin_amdgcn_mfma_f32_16x16x32_bf16(qf1, b1, a, 0, 0, 0);
    sc[tt] = a;
  }

  // mask + exact softmax (window fits in the 192 keys)
  float lrow[4];
#pragma unroll
  for (int r = 0; r < 4; r++) {
    int i = qw + quad * 4 + r;
    float mx = -3e38f;
#pragma unroll
    for (int tt = 0; tt < 12; tt++) {
      int t = t0 + tt * 16 + l15;
      bool ok = (t >= i - 64) && (t <= i + 64) && smask[tt * 16 + l15];
      float v = ok ? sc[tt][r] : -3e38f;
      sc[tt][r] = v;
      mx = fmaxf(mx, v);
    }
#pragma unroll
    for (int off = 1; off < 16; off <<= 1) mx = fmaxf(mx, __shfl_xor(mx, off));
    float sum = 0.f;
#pragma unroll
    for (int tt = 0; tt < 12; tt++) {
      float p = __expf(sc[tt][r] - mx);
      sc[tt][r] = p;
      sum += p;
    }
#pragma unroll
    for (int off = 1; off < 16; off <<= 1) sum += __shfl_xor(sum, off);
    lrow[r] = sum;
  }

  // P -> LDS (C-layout -> A-layout round trip)
  unsigned short* Pw = Ps[wave];
#pragma unroll
  for (int tt = 0; tt < 12; tt++)
#pragma unroll
    for (int r = 0; r < 4; r++)
      Pw[(quad * 4 + r) * 200 + tt * 16 + l15] = f2bf(sc[tt][r]);
  __syncthreads();

  // O = P @ V   (16 x 64)
  f32x4 o[4];
#pragma unroll
  for (int dt = 0; dt < 4; dt++) o[dt] = (f32x4){0.f, 0.f, 0.f, 0.f};
#pragma unroll
  for (int kt = 0; kt < 6; kt++) {
    short8 pf = *(const short8*)&Pw[l15 * 200 + kt * 32 + quad * 8];
#pragma unroll
    for (int dt = 0; dt < 4; dt++) {
      short8 vf = *(const short8*)&Vs[(dt * 16 + l15) * 200 + kt * 32 + quad * 8];
      o[dt] = __builtin_amdgcn_mfma_f32_16x16x32_bf16(pf, vf, o[dt], 0, 0, 0);
    }
  }

#pragma unroll
  for (int r = 0; r < 4; r++) {
    float inv = 1.f / lrow[r];
    int tok = b * SEQ + qw + quad * 4 + r;
    size_t base = (size_t)tok * 1024 + h * 64;
#pragma unroll
    for (int dt = 0; dt < 4; dt++)
      ob[base + dt * 16 + l15] = f2bf(o[dt][r] * inv);
  }
}

// --------------------------------------------------------------- gemm2 -----
__global__ __launch_bounds__(256) void gemm_out(
    const unsigned short* __restrict__ A,   // attn [8192][1024] bf16
    const unsigned short* __restrict__ W,   // Wo   [1024][1024] bf16
    float* __restrict__ out)                // [8192][1024] fp32
{
  __shared__ unsigned short As[128 * 32];
  __shared__ unsigned short Bs[128 * 32];
  const int tid  = threadIdx.x;
  const int wave = tid >> 6, lane = tid & 63;
  const int quad = lane >> 4, l15 = lane & 15;
  const int row0 = blockIdx.y * 128;
  const int col0 = blockIdx.x * 128;
  const int mrow = (wave >> 1) * 64;
  const int ncol = (wave & 1) * 64;

  f32x4 acc[4][4];
#pragma unroll
  for (int i = 0; i < 4; i++)
#pragma unroll
    for (int j = 0; j < 4; j++) acc[i][j] = (f32x4){0.f, 0.f, 0.f, 0.f};

  for (int k0 = 0; k0 < 1024; k0 += 32) {
#pragma unroll
    for (int i = 0; i < 2; i++) {
      int p = i * 256 + tid;
      int r = p >> 2, c = p & 3;
      gload_lds16(A + (size_t)(row0 + r) * 1024 + k0 + c * 8, &As[p * 8]);
      gload_lds16(W + (size_t)(col0 + r) * 1024 + k0 + c * 8, &Bs[p * 8]);
    }
    __syncthreads();
    short8 af[4], bf[4];
#pragma unroll
    for (int mt = 0; mt < 4; mt++)
      af[mt] = *(const short8*)&As[(mrow + mt * 16 + l15) * 32 + quad * 8];
#pragma unroll
    for (int nt = 0; nt < 4; nt++)
      bf[nt] = *(const short8*)&Bs[(ncol + nt * 16 + l15) * 32 + quad * 8];
#pragma unroll
    for (int mt = 0; mt < 4; mt++)
#pragma unroll
      for (int nt = 0; nt < 4; nt++)
        acc[mt][nt] = __builtin_amdgcn_mfma_f32_16x16x32_bf16(af[mt], bf[nt],
                                                              acc[mt][nt], 0, 0, 0);
    __syncthreads();
  }

  const int colw = col0 + ncol;
  const int rowg = row0 + mrow;
#pragma unroll
  for (int mt = 0; mt < 4; mt++)
#pragma unroll
    for (int r = 0; r < 4; r++) {
      int row = rowg + mt * 16 + quad * 4 + r;
#pragma unroll
      for (int nt = 0; nt < 4; nt++)
        out[(size_t)row * 1024 + colw + nt * 16 + l15] = acc[mt][nt][r];
    }
}

// ----------------------------------------------------------------- launch --
extern "C" void kernel_launch(void* const* d_in, const int* in_sizes, int n_in,
                              void* d_out, int out_size, void* d_ws, size_t ws_size,
                              hipStream_t stream) {
  const float* hidden = (const float*)d_in[0];
  // d_in[1]=cu_seqlens, d_in[2]=max_seqlen, d_in[3]=indices (unused: dense B*S)
  const int*   am     = (const int*)d_in[4];
  const float* Wqkv   = (const float*)d_in[5];
  const float* Wo     = (const float*)d_in[6];
  float* out = (float*)d_out;

  char* ws = (char*)d_ws;
  unsigned short* hb  = (unsigned short*)(ws);                     // 16 MB
  unsigned short* wqb = (unsigned short*)(ws + (size_t)(16 << 20)); //  6 MB
  unsigned short* wob = (unsigned short*)(ws + (size_t)(22 << 20)); //  2 MB
  unsigned short* qbf = (unsigned short*)(ws + (size_t)(24 << 20)); // 16 MB
  unsigned short* kbf = (unsigned short*)(ws + (size_t)(40 << 20)); // 16 MB
  unsigned short* vtb = (unsigned short*)(ws + (size_t)(56 << 20)); // 16 MB
  unsigned short* ab  = hb;   // alias: hidden-bf16 is dead after gemm1

  cvt_bf16<<<(2097152 + 255) / 256, 256, 0, stream>>>(hidden, hb, 2097152);
  cvt_bf16<<<(786432 + 255) / 256, 256, 0, stream>>>(Wqkv, wqb, 786432);
  cvt_bf16<<<(262144 + 255) / 256, 256, 0, stream>>>(Wo, wob, 262144);

  dim3 g1(24, 64);
  gemm_qkv_rope<<<g1, 256, 0, stream>>>(hb, wqb, qbf, kbf, vtb);

  dim3 g2(16, 16, 8);
  attn_win<<<g2, 256, 0, stream>>>(qbf, kbf, vtb, am, ab);

  dim3 g3(8, 64);
  gemm_out<<<g3, 256, 0, stream>>>(ab, wob, out);
}

// Round 3
// 247.390 us; speedup vs baseline: 1.0290x; 1.0290x over previous
//
#include <hip/hip_runtime.h>

// ---------------------------------------------------------------------------
// FlexBertUnpadRopeAttention  (B=8, S=1024, H=16, D=64, HIDDEN=1024, win=±64)
//   1) prep: fused fp32->bf16 cvt (hidden, Wqkv, Wo) + RoPE cos/sin table
//   2) gemm_qkv_rope: qkv = hidden @ Wqkv^T, fused RoPE(+q*0.125) via table,
//      writes q[b,h,s,d], k[b,h,s,d], v^T[b,h,d,s]  (bf16)
//   3) attn_win: 64-query tile vs 192-key window, exact softmax, MFMA
//   4) gemm_out: out = attn @ Wo^T  (fp32 out)
// MFMA 16x16x32 bf16 layouts (HW-verified):
//   A: lane holds A[m=lane&15][k=quad*8+j]   (16B row-contiguous)
//   B: lane holds B[k=quad*8+j][n=lane&15]   (16B row-contiguous in K)
//   C/D: lane holds D[row=quad*4+reg][col=lane&15]
// R2->R3: sincosf epilogue tail (~1500 VALU ops/thread) replaced by 256 KB
// cos/sin table; 3 cvt launches fused into 1 prep kernel.
// ---------------------------------------------------------------------------

typedef __attribute__((ext_vector_type(8))) short short8;
typedef __attribute__((ext_vector_type(4))) float f32x4;

#define SEQ   1024
#define NHEAD 16
#define HEADD 64
#define NTOK  8192

__device__ __forceinline__ unsigned short f2bf(float x) {
  unsigned u = __float_as_uint(x);
  u += 0x7fffu + ((u >> 16) & 1u);          // RNE
  return (unsigned short)(u >> 16);
}

__device__ __forceinline__ void gload_lds16(const void* g, void* l) {
  __builtin_amdgcn_global_load_lds((__attribute__((address_space(1))) void*)(g),
                                   (__attribute__((address_space(3))) void*)(l),
                                   16, 0, 0);
}

// ---------------------------------------------------------------- prep -----
// blocks [0,8192): hidden cvt; [8192,11264): Wqkv; [11264,12288): Wo;
// [12288,12416): RoPE table tab[s*32+d] = (cos(s*invf_d), sin(s*invf_d))
__global__ __launch_bounds__(256) void prep(
    const float* __restrict__ hidden, const float* __restrict__ Wqkv,
    const float* __restrict__ Wo,
    unsigned short* __restrict__ hb, unsigned short* __restrict__ wqb,
    unsigned short* __restrict__ wob, float2* __restrict__ tab) {
  int bid = blockIdx.x;
  const float* in; unsigned short* out; int i;
  if (bid < 8192)       { in = hidden; out = hb;  i = bid * 256 + threadIdx.x; }
  else if (bid < 11264) { in = Wqkv;   out = wqb; i = (bid - 8192) * 256 + threadIdx.x; }
  else if (bid < 12288) { in = Wo;     out = wob; i = (bid - 11264) * 256 + threadIdx.x; }
  else {
    int j = (bid - 12288) * 256 + threadIdx.x;    // 0..32767
    int s = j >> 5, d = j & 31;
    float inv = exp2f(-(float)d * 0.41524101186092034f); // 10000^(-d/32)
    float sn, cs;
    sincosf((float)s * inv, &sn, &cs);
    tab[j] = make_float2(cs, sn);
    return;
  }
  float4 v = ((const float4*)in)[i];
  ushort4 o;
  o.x = f2bf(v.x); o.y = f2bf(v.y); o.z = f2bf(v.z); o.w = f2bf(v.w);
  ((ushort4*)out)[i] = o;
}

// --------------------------------------------------------- gemm1 + rope ----
__global__ __launch_bounds__(256) void gemm_qkv_rope(
    const unsigned short* __restrict__ A,   // [8192][1024] bf16
    const unsigned short* __restrict__ W,   // [3072][1024] bf16
    const float2* __restrict__ tab,         // [1024][32] (cos,sin)
    unsigned short* __restrict__ qb,        // [B][H][S][D]
    unsigned short* __restrict__ kb,        // [B][H][S][D]
    unsigned short* __restrict__ vt)        // [B][H][D][S]
{
  __shared__ unsigned short As[128 * 32];
  __shared__ unsigned short Bs[128 * 32];
  const int tid  = threadIdx.x;
  const int wave = tid >> 6, lane = tid & 63;
  const int quad = lane >> 4, l15 = lane & 15;
  const int row0 = blockIdx.y * 128;
  const int col0 = blockIdx.x * 128;
  const int mrow = (wave >> 1) * 64;        // wave M offset in tile
  const int ncol = (wave & 1) * 64;         // wave N offset in tile

  f32x4 acc[4][4];
#pragma unroll
  for (int i = 0; i < 4; i++)
#pragma unroll
    for (int j = 0; j < 4; j++) acc[i][j] = (f32x4){0.f, 0.f, 0.f, 0.f};

  for (int k0 = 0; k0 < 1024; k0 += 32) {
#pragma unroll
    for (int i = 0; i < 2; i++) {           // stage 8KB A + 8KB B, 16B/lane
      int p = i * 256 + tid;
      int r = p >> 2, c = p & 3;
      gload_lds16(A + (size_t)(row0 + r) * 1024 + k0 + c * 8, &As[p * 8]);
      gload_lds16(W + (size_t)(col0 + r) * 1024 + k0 + c * 8, &Bs[p * 8]);
    }
    __syncthreads();
    short8 af[4], bf[4];
#pragma unroll
    for (int mt = 0; mt < 4; mt++)
      af[mt] = *(const short8*)&As[(mrow + mt * 16 + l15) * 32 + quad * 8];
#pragma unroll
    for (int nt = 0; nt < 4; nt++)
      bf[nt] = *(const short8*)&Bs[(ncol + nt * 16 + l15) * 32 + quad * 8];
#pragma unroll
    for (int mt = 0; mt < 4; mt++)
#pragma unroll
      for (int nt = 0; nt < 4; nt++)
        acc[mt][nt] = __builtin_amdgcn_mfma_f32_16x16x32_bf16(af[mt], bf[nt],
                                                              acc[mt][nt], 0, 0, 0);
    __syncthreads();
  }

  // epilogue: this wave's 64 cols == one head of one {q,k,v} section
  const int colw  = col0 + ncol;            // multiple of 64
  const int which = colw >> 10;             // 0=q 1=k 2=v
  const int h     = (colw >> 6) & 15;
  const int rowg  = row0 + mrow;

  if (which == 2) {                         // V: transposed, 8B-packed stores
#pragma unroll
    for (int mt = 0; mt < 4; mt++) {
      int rbase = rowg + mt * 16 + quad * 4;
      int b = rbase >> 10, s = rbase & 1023;
#pragma unroll
      for (int c = 0; c < 4; c++) {
        int d = c * 16 + l15;
        ushort4 o;
        o.x = f2bf(acc[mt][c][0]); o.y = f2bf(acc[mt][c][1]);
        o.z = f2bf(acc[mt][c][2]); o.w = f2bf(acc[mt][c][3]);
        *(ushort4*)&vt[((size_t)((b * 16 + h) * 64 + d)) * 1024 + s] = o;
      }
    }
  } else {                                  // Q/K: in-register RoPE via table
    unsigned short* dst = (which == 0) ? qb : kb;
    const float scale = (which == 0) ? 0.125f : 1.0f;
#pragma unroll
    for (int mt = 0; mt < 4; mt++) {
#pragma unroll
      for (int r = 0; r < 4; r++) {
        int row = rowg + mt * 16 + quad * 4 + r;
        int b = row >> 10, s = row & 1023;
        size_t base = (size_t)((b * 16 + h) * 1024 + s) * 64;
        float2 t0 = tab[s * 32 + l15];
        float2 t1 = tab[s * 32 + 16 + l15];
        float x1a = acc[mt][0][r], x2a = acc[mt][2][r];   // d=l15, d+32
        float x1b = acc[mt][1][r], x2b = acc[mt][3][r];   // d=16+l15, d+32
        dst[base + l15]           = f2bf((x1a * t0.x - x2a * t0.y) * scale);
        dst[base + 32 + l15]      = f2bf((x2a * t0.x + x1a * t0.y) * scale);
        dst[base + 16 + l15]      = f2bf((x1b * t1.x - x2b * t1.y) * scale);
        dst[base + 48 + l15]      = f2bf((x2b * t1.x + x1b * t1.y) * scale);
      }
    }
  }
}

// ------------------------------------------------------------- attention ---
__global__ __launch_bounds__(256) void attn_win(
    const unsigned short* __restrict__ qb,
    const unsigned short* __restrict__ kb,
    const unsigned short* __restrict__ vt,
    const int* __restrict__ am,             // attn_mask [B][S]
    unsigned short* __restrict__ ob)        // [8192][1024] bf16
{
  __shared__ unsigned short Ks[192 * 72];    // keys, +8 pad
  __shared__ unsigned short Vs[64 * 200];    // V^T,  +8 pad
  __shared__ unsigned short Ps[4][16 * 200]; // per-wave P, +8 pad
  __shared__ unsigned short smask[192];

  const int tid  = threadIdx.x;
  const int wave = tid >> 6, lane = tid & 63;
  const int quad = lane >> 4, l15 = lane & 15;
  const int qs = blockIdx.x * 64;
  const int h  = blockIdx.y, b = blockIdx.z;
  const size_t hb = (size_t)(b * 16 + h);
  const unsigned short* Qg = qb + hb * SEQ * 64;
  const unsigned short* Kg = kb + hb * SEQ * 64;
  const unsigned short* Vg = vt + hb * 64 * SEQ;
  const int t0 = qs - 64;

  // stage K: 192 rows x 8 chunks(16B) = full 64-dim rows
#pragma unroll
  for (int i = 0; i < 6; i++) {
    int p = i * 256 + tid;
    int r = p >> 3, c = p & 7;
    int t = t0 + r; t = t < 0 ? 0 : (t > 1023 ? 1023 : t);   // garbage masked
    *(short8*)&Ks[r * 72 + c * 8] = *(const short8*)&Kg[(size_t)t * 64 + c * 8];
  }
  // stage V^T: 64 rows x 24 chunks
#pragma unroll
  for (int i = 0; i < 6; i++) {
    int p = i * 256 + tid;
    int d = p / 24, c = p % 24;
    int t = t0 + c * 8; t = t < 0 ? 0 : (t > 1016 ? 1016 : t);
    *(short8*)&Vs[d * 200 + c * 8] = *(const short8*)&Vg[(size_t)d * SEQ + t];
  }
  if (tid < 192) {
    int t = t0 + tid;
    smask[tid] = (t >= 0 && t < SEQ) ? (unsigned short)(am[b * SEQ + t] != 0) : 0;
  }
  __syncthreads();

  // Q fragments straight from global (A-operand is row-contiguous)
  const int qw = qs + wave * 16;
  short8 qf0 = *(const short8*)&Qg[(size_t)(qw + l15) * 64 + quad * 8];
  short8 qf1 = *(const short8*)&Qg[(size_t)(qw + l15) * 64 + 32 + quad * 8];

  // scores: 16 x 192
  f32x4 sc[12];
#pragma unroll
  for (int tt = 0; tt < 12; tt++) {
    short8 b0 = *(const short8*)&Ks[(tt * 16 + l15) * 72 + quad * 8];
    short8 b1 = *(const short8*)&Ks[(tt * 16 + l15) * 72 + 32 + quad * 8];
    f32x4 a = (f32x4){0.f, 0.f, 0.f, 0.f};
    a = __builtin_amdgcn_mfma_f32_16x16x32_bf16(qf0, b0, a, 0, 0, 0);
    a = __builtin_amdgcn_mfma_f32_16x16x32_bf16(qf1, b1, a, 0, 0, 0);
    sc[tt] = a;
  }

  // mask + exact softmax (window fits in the 192 keys)
  float lrow[4];
#pragma unroll
  for (int r = 0; r < 4; r++) {
    int i = qw + quad * 4 + r;
    float mx = -3e38f;
#pragma unroll
    for (int tt = 0; tt < 12; tt++) {
      int t = t0 + tt * 16 + l15;
      bool ok = (t >= i - 64) && (t <= i + 64) && smask[tt * 16 + l15];
      float v = ok ? sc[tt][r] : -3e38f;
      sc[tt][r] = v;
      mx = fmaxf(mx, v);
    }
#pragma unroll
    for (int off = 1; off < 16; off <<= 1) mx = fmaxf(mx, __shfl_xor(mx, off));
    float sum = 0.f;
#pragma unroll
    for (int tt = 0; tt < 12; tt++) {
      float p = __expf(sc[tt][r] - mx);
      sc[tt][r] = p;
      sum += p;
    }
#pragma unroll
    for (int off = 1; off < 16; off <<= 1) sum += __shfl_xor(sum, off);
    lrow[r] = sum;
  }

  // P -> LDS (C-layout -> A-layout round trip)
  unsigned short* Pw = Ps[wave];
#pragma unroll
  for (int tt = 0; tt < 12; tt++)
#pragma unroll
    for (int r = 0; r < 4; r++)
      Pw[(quad * 4 + r) * 200 + tt * 16 + l15] = f2bf(sc[tt][r]);
  __syncthreads();

  // O = P @ V   (16 x 64)
  f32x4 o[4];
#pragma unroll
  for (int dt = 0; dt < 4; dt++) o[dt] = (f32x4){0.f, 0.f, 0.f, 0.f};
#pragma unroll
  for (int kt = 0; kt < 6; kt++) {
    short8 pf = *(const short8*)&Pw[l15 * 200 + kt * 32 + quad * 8];
#pragma unroll
    for (int dt = 0; dt < 4; dt++) {
      short8 vf = *(const short8*)&Vs[(dt * 16 + l15) * 200 + kt * 32 + quad * 8];
      o[dt] = __builtin_amdgcn_mfma_f32_16x16x32_bf16(pf, vf, o[dt], 0, 0, 0);
    }
  }

#pragma unroll
  for (int r = 0; r < 4; r++) {
    float inv = 1.f / lrow[r];
    int tok = b * SEQ + qw + quad * 4 + r;
    size_t base = (size_t)tok * 1024 + h * 64;
#pragma unroll
    for (int dt = 0; dt < 4; dt++)
      ob[base + dt * 16 + l15] = f2bf(o[dt][r] * inv);
  }
}

// --------------------------------------------------------------- gemm2 -----
__global__ __launch_bounds__(256) void gemm_out(
    const unsigned short* __restrict__ A,   // attn [8192][1024] bf16
    const unsigned short* __restrict__ W,   // Wo   [1024][1024] bf16
    float* __restrict__ out)                // [8192][1024] fp32
{
  __shared__ unsigned short As[128 * 32];
  __shared__ unsigned short Bs[128 * 32];
  const int tid  = threadIdx.x;
  const int wave = tid >> 6, lane = tid & 63;
  const int quad = lane >> 4, l15 = lane & 15;
  const int row0 = blockIdx.y * 128;
  const int col0 = blockIdx.x * 128;
  const int mrow = (wave >> 1) * 64;
  const int ncol = (wave & 1) * 64;

  f32x4 acc[4][4];
#pragma unroll
  for (int i = 0; i < 4; i++)
#pragma unroll
    for (int j = 0; j < 4; j++) acc[i][j] = (f32x4){0.f, 0.f, 0.f, 0.f};

  for (int k0 = 0; k0 < 1024; k0 += 32) {
#pragma unroll
    for (int i = 0; i < 2; i++) {
      int p = i * 256 + tid;
      int r = p >> 2, c = p & 3;
      gload_lds16(A + (size_t)(row0 + r) * 1024 + k0 + c * 8, &As[p * 8]);
      gload_lds16(W + (size_t)(col0 + r) * 1024 + k0 + c * 8, &Bs[p * 8]);
    }
    __syncthreads();
    short8 af[4], bf[4];
#pragma unroll
    for (int mt = 0; mt < 4; mt++)
      af[mt] = *(const short8*)&As[(mrow + mt * 16 + l15) * 32 + quad * 8];
#pragma unroll
    for (int nt = 0; nt < 4; nt++)
      bf[nt] = *(const short8*)&Bs[(ncol + nt * 16 + l15) * 32 + quad * 8];
#pragma unroll
    for (int mt = 0; mt < 4; mt++)
#pragma unroll
      for (int nt = 0; nt < 4; nt++)
        acc[mt][nt] = __builtin_amdgcn_mfma_f32_16x16x32_bf16(af[mt], bf[nt],
                                                              acc[mt][nt], 0, 0, 0);
    __syncthreads();
  }

  const int colw = col0 + ncol;
  const int rowg = row0 + mrow;
#pragma unroll
  for (int mt = 0; mt < 4; mt++)
#pragma unroll
    for (int r = 0; r < 4; r++) {
      int row = rowg + mt * 16 + quad * 4 + r;
#pragma unroll
      for (int nt = 0; nt < 4; nt++)
        out[(size_t)row * 1024 + colw + nt * 16 + l15] = acc[mt][nt][r];
    }
}

// ----------------------------------------------------------------- launch --
extern "C" void kernel_launch(void* const* d_in, const int* in_sizes, int n_in,
                              void* d_out, int out_size, void* d_ws, size_t ws_size,
                              hipStream_t stream) {
  const float* hidden = (const float*)d_in[0];
  // d_in[1]=cu_seqlens, d_in[2]=max_seqlen, d_in[3]=indices (unused: dense B*S)
  const int*   am     = (const int*)d_in[4];
  const float* Wqkv   = (const float*)d_in[5];
  const float* Wo     = (const float*)d_in[6];
  float* out = (float*)d_out;

  char* ws = (char*)d_ws;
  unsigned short* hb  = (unsigned short*)(ws);                      // 16 MB
  unsigned short* wqb = (unsigned short*)(ws + (size_t)(16 << 20)); //  6 MB
  unsigned short* wob = (unsigned short*)(ws + (size_t)(22 << 20)); //  2 MB
  unsigned short* qbf = (unsigned short*)(ws + (size_t)(24 << 20)); // 16 MB
  unsigned short* kbf = (unsigned short*)(ws + (size_t)(40 << 20)); // 16 MB
  unsigned short* vtb = (unsigned short*)(ws + (size_t)(56 << 20)); // 16 MB
  float2*         tab = (float2*)(ws + (size_t)(72 << 20));         // 256 KB
  unsigned short* ab  = hb;   // alias: hidden-bf16 is dead after gemm1

  prep<<<12416, 256, 0, stream>>>(hidden, Wqkv, Wo, hb, wqb, wob, tab);

  dim3 g1(24, 64);
  gemm_qkv_rope<<<g1, 256, 0, stream>>>(hb, wqb, tab, qbf, kbf, vtb);

  dim3 g2(16, 16, 8);
  attn_win<<<g2, 256, 0, stream>>>(qbf, kbf, vtb, am, ab);

  dim3 g3(8, 64);
  gemm_out<<<g3, 256, 0, stream>>>(ab, wob, out);
}

// Round 4
// 231.848 us; speedup vs baseline: 1.0980x; 1.0670x over previous
//
#include <hip/hip_runtime.h>

// ---------------------------------------------------------------------------
// FlexBertUnpadRopeAttention  (B=8, S=1024, H=16, D=64, HIDDEN=1024, win=±64)
//   1) prep: fused fp32->bf16 cvt (hidden, Wqkv, Wo) + RoPE cos/sin table
//   2) gemm_qkv_rope: qkv = hidden @ Wqkv^T, fused RoPE(+q*0.125) via table
//   3) attn_win: 64-query tile vs 192-key window, exact softmax, MFMA
//   4) gemm_out: out = attn @ Wo^T  (fp32 out)
// R3->R4: attn LDS 79->54 KB (P overlays K after extra barrier) for >=2
// blocks/CU; XCD-supertile swizzles on both GEMMs (A-slab L2-resident) and
// attn ((b,h) pinned to one XCD).
// ---------------------------------------------------------------------------

typedef __attribute__((ext_vector_type(8))) short short8;
typedef __attribute__((ext_vector_type(4))) float f32x4;

#define SEQ   1024
#define NHEAD 16
#define HEADD 64
#define NTOK  8192

__device__ __forceinline__ unsigned short f2bf(float x) {
  unsigned u = __float_as_uint(x);
  u += 0x7fffu + ((u >> 16) & 1u);          // RNE
  return (unsigned short)(u >> 16);
}

__device__ __forceinline__ void gload_lds16(const void* g, void* l) {
  __builtin_amdgcn_global_load_lds((__attribute__((address_space(1))) void*)(g),
                                   (__attribute__((address_space(3))) void*)(l),
                                   16, 0, 0);
}

// ---------------------------------------------------------------- prep -----
__global__ __launch_bounds__(256) void prep(
    const float* __restrict__ hidden, const float* __restrict__ Wqkv,
    const float* __restrict__ Wo,
    unsigned short* __restrict__ hb, unsigned short* __restrict__ wqb,
    unsigned short* __restrict__ wob, float2* __restrict__ tab) {
  int bid = blockIdx.x;
  const float* in; unsigned short* out; int i;
  if (bid < 8192)       { in = hidden; out = hb;  i = bid * 256 + threadIdx.x; }
  else if (bid < 11264) { in = Wqkv;   out = wqb; i = (bid - 8192) * 256 + threadIdx.x; }
  else if (bid < 12288) { in = Wo;     out = wob; i = (bid - 11264) * 256 + threadIdx.x; }
  else {
    int j = (bid - 12288) * 256 + threadIdx.x;    // 0..32767
    int s = j >> 5, d = j & 31;
    float inv = exp2f(-(float)d * 0.41524101186092034f); // 10000^(-d/32)
    float sn, cs;
    sincosf((float)s * inv, &sn, &cs);
    tab[j] = make_float2(cs, sn);
    return;
  }
  float4 v = ((const float4*)in)[i];
  ushort4 o;
  o.x = f2bf(v.x); o.y = f2bf(v.y); o.z = f2bf(v.z); o.w = f2bf(v.w);
  ((ushort4*)out)[i] = o;
}

// --------------------------------------------------------- gemm1 + rope ----
// 1-D grid of 1536; xcd=bid%8 owns rows [xcd*8, xcd*8+8) x all 24 col-blocks.
__global__ __launch_bounds__(256) void gemm_qkv_rope(
    const unsigned short* __restrict__ A,   // [8192][1024] bf16
    const unsigned short* __restrict__ W,   // [3072][1024] bf16
    const float2* __restrict__ tab,         // [1024][32] (cos,sin)
    unsigned short* __restrict__ qb,        // [B][H][S][D]
    unsigned short* __restrict__ kb,        // [B][H][S][D]
    unsigned short* __restrict__ vt)        // [B][H][D][S]
{
  __shared__ unsigned short As[128 * 32];
  __shared__ unsigned short Bs[128 * 32];
  const int tid  = threadIdx.x;
  const int wave = tid >> 6, lane = tid & 63;
  const int quad = lane >> 4, l15 = lane & 15;
  const int bid  = blockIdx.x;
  const int xcd  = bid & 7, idx = bid >> 3;          // idx in [0,192)
  const int rb   = xcd * 8 + (idx & 7);              // [0,64)
  const int cb   = idx >> 3;                         // [0,24)
  const int row0 = rb * 128;
  const int col0 = cb * 128;
  const int mrow = (wave >> 1) * 64;
  const int ncol = (wave & 1) * 64;

  f32x4 acc[4][4];
#pragma unroll
  for (int i = 0; i < 4; i++)
#pragma unroll
    for (int j = 0; j < 4; j++) acc[i][j] = (f32x4){0.f, 0.f, 0.f, 0.f};

  for (int k0 = 0; k0 < 1024; k0 += 32) {
#pragma unroll
    for (int i = 0; i < 2; i++) {           // stage 8KB A + 8KB B, 16B/lane
      int p = i * 256 + tid;
      int r = p >> 2, c = p & 3;
      gload_lds16(A + (size_t)(row0 + r) * 1024 + k0 + c * 8, &As[p * 8]);
      gload_lds16(W + (size_t)(col0 + r) * 1024 + k0 + c * 8, &Bs[p * 8]);
    }
    __syncthreads();
    short8 af[4], bf[4];
#pragma unroll
    for (int mt = 0; mt < 4; mt++)
      af[mt] = *(const short8*)&As[(mrow + mt * 16 + l15) * 32 + quad * 8];
#pragma unroll
    for (int nt = 0; nt < 4; nt++)
      bf[nt] = *(const short8*)&Bs[(ncol + nt * 16 + l15) * 32 + quad * 8];
#pragma unroll
    for (int mt = 0; mt < 4; mt++)
#pragma unroll
      for (int nt = 0; nt < 4; nt++)
        acc[mt][nt] = __builtin_amdgcn_mfma_f32_16x16x32_bf16(af[mt], bf[nt],
                                                              acc[mt][nt], 0, 0, 0);
    __syncthreads();
  }

  // epilogue: this wave's 64 cols == one head of one {q,k,v} section
  const int colw  = col0 + ncol;            // multiple of 64
  const int which = colw >> 10;             // 0=q 1=k 2=v
  const int h     = (colw >> 6) & 15;
  const int rowg  = row0 + mrow;

  if (which == 2) {                         // V: transposed, 8B-packed stores
#pragma unroll
    for (int mt = 0; mt < 4; mt++) {
      int rbase = rowg + mt * 16 + quad * 4;
      int b = rbase >> 10, s = rbase & 1023;
#pragma unroll
      for (int c = 0; c < 4; c++) {
        int d = c * 16 + l15;
        ushort4 o;
        o.x = f2bf(acc[mt][c][0]); o.y = f2bf(acc[mt][c][1]);
        o.z = f2bf(acc[mt][c][2]); o.w = f2bf(acc[mt][c][3]);
        *(ushort4*)&vt[((size_t)((b * 16 + h) * 64 + d)) * 1024 + s] = o;
      }
    }
  } else {                                  // Q/K: in-register RoPE via table
    unsigned short* dst = (which == 0) ? qb : kb;
    const float scale = (which == 0) ? 0.125f : 1.0f;
#pragma unroll
    for (int mt = 0; mt < 4; mt++) {
#pragma unroll
      for (int r = 0; r < 4; r++) {
        int row = rowg + mt * 16 + quad * 4 + r;
        int b = row >> 10, s = row & 1023;
        size_t base = (size_t)((b * 16 + h) * 1024 + s) * 64;
        float2 t0 = tab[s * 32 + l15];
        float2 t1 = tab[s * 32 + 16 + l15];
        float x1a = acc[mt][0][r], x2a = acc[mt][2][r];   // d=l15, d+32
        float x1b = acc[mt][1][r], x2b = acc[mt][3][r];   // d=16+l15, d+32
        dst[base + l15]           = f2bf((x1a * t0.x - x2a * t0.y) * scale);
        dst[base + 32 + l15]      = f2bf((x2a * t0.x + x1a * t0.y) * scale);
        dst[base + 16 + l15]      = f2bf((x1b * t1.x - x2b * t1.y) * scale);
        dst[base + 48 + l15]      = f2bf((x2b * t1.x + x1b * t1.y) * scale);
      }
    }
  }
}

// ------------------------------------------------------------- attention ---
// grid (128,16): x = b*16+h (xcd = x%8 pins (b,h-mod-8) streams per XCD),
// y = q-tile. LDS: P overlays Ks after an extra barrier (54 KB total).
__global__ __launch_bounds__(256) void attn_win(
    const unsigned short* __restrict__ qb,
    const unsigned short* __restrict__ kb,
    const unsigned short* __restrict__ vt,
    const int* __restrict__ am,             // attn_mask [B][S]
    unsigned short* __restrict__ ob)        // [8192][1024] bf16
{
  __shared__ unsigned short Ks[192 * 72];    // keys (+8 pad); later holds P
  __shared__ unsigned short Vs[64 * 200];    // V^T (+8 pad)
  __shared__ unsigned short smask[192];

  const int tid  = threadIdx.x;
  const int wave = tid >> 6, lane = tid & 63;
  const int quad = lane >> 4, l15 = lane & 15;
  const int b  = blockIdx.x >> 4, h = blockIdx.x & 15;
  const int qs = blockIdx.y * 64;
  const size_t hb = (size_t)(b * 16 + h);
  const unsigned short* Qg = qb + hb * SEQ * 64;
  const unsigned short* Kg = kb + hb * SEQ * 64;
  const unsigned short* Vg = vt + hb * 64 * SEQ;
  const int t0 = qs - 64;

  // stage K: 192 rows x 8 chunks(16B) = full 64-dim rows
#pragma unroll
  for (int i = 0; i < 6; i++) {
    int p = i * 256 + tid;
    int r = p >> 3, c = p & 7;
    int t = t0 + r; t = t < 0 ? 0 : (t > 1023 ? 1023 : t);   // garbage masked
    *(short8*)&Ks[r * 72 + c * 8] = *(const short8*)&Kg[(size_t)t * 64 + c * 8];
  }
  // stage V^T: 64 rows x 24 chunks
#pragma unroll
  for (int i = 0; i < 6; i++) {
    int p = i * 256 + tid;
    int d = p / 24, c = p % 24;
    int t = t0 + c * 8; t = t < 0 ? 0 : (t > 1016 ? 1016 : t);
    *(short8*)&Vs[d * 200 + c * 8] = *(const short8*)&Vg[(size_t)d * SEQ + t];
  }
  if (tid < 192) {
    int t = t0 + tid;
    smask[tid] = (t >= 0 && t < SEQ) ? (unsigned short)(am[b * SEQ + t] != 0) : 0;
  }
  __syncthreads();

  // Q fragments straight from global (A-operand is row-contiguous)
  const int qw = qs + wave * 16;
  short8 qf0 = *(const short8*)&Qg[(size_t)(qw + l15) * 64 + quad * 8];
  short8 qf1 = *(const short8*)&Qg[(size_t)(qw + l15) * 64 + 32 + quad * 8];

  // scores: 16 x 192
  f32x4 sc[12];
#pragma unroll
  for (int tt = 0; tt < 12; tt++) {
    short8 b0 = *(const short8*)&Ks[(tt * 16 + l15) * 72 + quad * 8];
    short8 b1 = *(const short8*)&Ks[(tt * 16 + l15) * 72 + 32 + quad * 8];
    f32x4 a = (f32x4){0.f, 0.f, 0.f, 0.f};
    a = __builtin_amdgcn_mfma_f32_16x16x32_bf16(qf0, b0, a, 0, 0, 0);
    a = __builtin_amdgcn_mfma_f32_16x16x32_bf16(qf1, b1, a, 0, 0, 0);
    sc[tt] = a;
  }

  // mask + exact softmax (window fits in the 192 keys)
  float lrow[4];
#pragma unroll
  for (int r = 0; r < 4; r++) {
    int i = qw + quad * 4 + r;
    float mx = -3e38f;
#pragma unroll
    for (int tt = 0; tt < 12; tt++) {
      int t = t0 + tt * 16 + l15;
      bool ok = (t >= i - 64) && (t <= i + 64) && smask[tt * 16 + l15];
      float v = ok ? sc[tt][r] : -3e38f;
      sc[tt][r] = v;
      mx = fmaxf(mx, v);
    }
#pragma unroll
    for (int off = 1; off < 16; off <<= 1) mx = fmaxf(mx, __shfl_xor(mx, off));
    float sum = 0.f;
#pragma unroll
    for (int tt = 0; tt < 12; tt++) {
      float p = __expf(sc[tt][r] - mx);
      sc[tt][r] = p;
      sum += p;
    }
#pragma unroll
    for (int off = 1; off < 16; off <<= 1) sum += __shfl_xor(sum, off);
    lrow[r] = sum;
  }

  __syncthreads();                          // all waves done reading Ks
  // P -> LDS overlay on Ks (C-layout -> A-layout round trip)
  unsigned short* Pw = &Ks[wave * (16 * 200)];   // 4*3200 <= 13824 shorts
#pragma unroll
  for (int tt = 0; tt < 12; tt++)
#pragma unroll
    for (int r = 0; r < 4; r++)
      Pw[(quad * 4 + r) * 200 + tt * 16 + l15] = f2bf(sc[tt][r]);
  __syncthreads();

  // O = P @ V   (16 x 64)
  f32x4 o[4];
#pragma unroll
  for (int dt = 0; dt < 4; dt++) o[dt] = (f32x4){0.f, 0.f, 0.f, 0.f};
#pragma unroll
  for (int kt = 0; kt < 6; kt++) {
    short8 pf = *(const short8*)&Pw[l15 * 200 + kt * 32 + quad * 8];
#pragma unroll
    for (int dt = 0; dt < 4; dt++) {
      short8 vf = *(const short8*)&Vs[(dt * 16 + l15) * 200 + kt * 32 + quad * 8];
      o[dt] = __builtin_amdgcn_mfma_f32_16x16x32_bf16(pf, vf, o[dt], 0, 0, 0);
    }
  }

#pragma unroll
  for (int r = 0; r < 4; r++) {
    float inv = 1.f / lrow[r];
    int tok = b * SEQ + qw + quad * 4 + r;
    size_t base = (size_t)tok * 1024 + h * 64;
#pragma unroll
    for (int dt = 0; dt < 4; dt++)
      ob[base + dt * 16 + l15] = f2bf(o[dt][r] * inv);
  }
}

// --------------------------------------------------------------- gemm2 -----
// 1-D grid of 512; xcd=bid%8 owns rows [xcd*8, xcd*8+8) x all 8 col-blocks.
__global__ __launch_bounds__(256) void gemm_out(
    const unsigned short* __restrict__ A,   // attn [8192][1024] bf16
    const unsigned short* __restrict__ W,   // Wo   [1024][1024] bf16
    float* __restrict__ out)                // [8192][1024] fp32
{
  __shared__ unsigned short As[128 * 32];
  __shared__ unsigned short Bs[128 * 32];
  const int tid  = threadIdx.x;
  const int wave = tid >> 6, lane = tid & 63;
  const int quad = lane >> 4, l15 = lane & 15;
  const int bid  = blockIdx.x;
  const int xcd  = bid & 7, idx = bid >> 3;          // idx in [0,64)
  const int row0 = (xcd * 8 + (idx & 7)) * 128;
  const int col0 = (idx >> 3) * 128;
  const int mrow = (wave >> 1) * 64;
  const int ncol = (wave & 1) * 64;

  f32x4 acc[4][4];
#pragma unroll
  for (int i = 0; i < 4; i++)
#pragma unroll
    for (int j = 0; j < 4; j++) acc[i][j] = (f32x4){0.f, 0.f, 0.f, 0.f};

  for (int k0 = 0; k0 < 1024; k0 += 32) {
#pragma unroll
    for (int i = 0; i < 2; i++) {
      int p = i * 256 + tid;
      int r = p >> 2, c = p & 3;
      gload_lds16(A + (size_t)(row0 + r) * 1024 + k0 + c * 8, &As[p * 8]);
      gload_lds16(W + (size_t)(col0 + r) * 1024 + k0 + c * 8, &Bs[p * 8]);
    }
    __syncthreads();
    short8 af[4], bf[4];
#pragma unroll
    for (int mt = 0; mt < 4; mt++)
      af[mt] = *(const short8*)&As[(mrow + mt * 16 + l15) * 32 + quad * 8];
#pragma unroll
    for (int nt = 0; nt < 4; nt++)
      bf[nt] = *(const short8*)&Bs[(ncol + nt * 16 + l15) * 32 + quad * 8];
#pragma unroll
    for (int mt = 0; mt < 4; mt++)
#pragma unroll
      for (int nt = 0; nt < 4; nt++)
        acc[mt][nt] = __builtin_amdgcn_mfma_f32_16x16x32_bf16(af[mt], bf[nt],
                                                              acc[mt][nt], 0, 0, 0);
    __syncthreads();
  }

  const int colw = col0 + ncol;
  const int rowg = row0 + mrow;
#pragma unroll
  for (int mt = 0; mt < 4; mt++)
#pragma unroll
    for (int r = 0; r < 4; r++) {
      int row = rowg + mt * 16 + quad * 4 + r;
#pragma unroll
      for (int nt = 0; nt < 4; nt++)
        out[(size_t)row * 1024 + colw + nt * 16 + l15] = acc[mt][nt][r];
    }
}

// ----------------------------------------------------------------- launch --
extern "C" void kernel_launch(void* const* d_in, const int* in_sizes, int n_in,
                              void* d_out, int out_size, void* d_ws, size_t ws_size,
                              hipStream_t stream) {
  const float* hidden = (const float*)d_in[0];
  // d_in[1]=cu_seqlens, d_in[2]=max_seqlen, d_in[3]=indices (unused: dense B*S)
  const int*   am     = (const int*)d_in[4];
  const float* Wqkv   = (const float*)d_in[5];
  const float* Wo     = (const float*)d_in[6];
  float* out = (float*)d_out;

  char* ws = (char*)d_ws;
  unsigned short* hb  = (unsigned short*)(ws);                      // 16 MB
  unsigned short* wqb = (unsigned short*)(ws + (size_t)(16 << 20)); //  6 MB
  unsigned short* wob = (unsigned short*)(ws + (size_t)(22 << 20)); //  2 MB
  unsigned short* qbf = (unsigned short*)(ws + (size_t)(24 << 20)); // 16 MB
  unsigned short* kbf = (unsigned short*)(ws + (size_t)(40 << 20)); // 16 MB
  unsigned short* vtb = (unsigned short*)(ws + (size_t)(56 << 20)); // 16 MB
  float2*         tab = (float2*)(ws + (size_t)(72 << 20));         // 256 KB
  unsigned short* ab  = hb;   // alias: hidden-bf16 is dead after gemm1

  prep<<<12416, 256, 0, stream>>>(hidden, Wqkv, Wo, hb, wqb, wob, tab);

  gemm_qkv_rope<<<1536, 256, 0, stream>>>(hb, wqb, tab, qbf, kbf, vtb);

  dim3 g2(128, 16);
  attn_win<<<g2, 256, 0, stream>>>(qbf, kbf, vtb, am, ab);

  gemm_out<<<512, 256, 0, stream>>>(ab, wob, out);
}